// Round 6
// baseline (276.474 us; speedup 1.0000x reference)
//
#include <hip/hip_runtime.h>

typedef __attribute__((ext_vector_type(8))) short bf16x8;
typedef __attribute__((ext_vector_type(4))) float f32x4;
typedef __attribute__((ext_vector_type(2))) unsigned int u32x2;
typedef unsigned int u32;
typedef unsigned short u16;

constexpr int Bb = 4, S = 2048, D = 1024, H = 16, DK = 64, M = Bb * S;

#if __has_builtin(__builtin_amdgcn_exp2f)
#define EXP2F __builtin_amdgcn_exp2f
#else
#define EXP2F exp2f
#endif

__device__ __forceinline__ u16 f2bf(float f) {
  u32 u = __float_as_uint(f);
  return (u16)((u + 0x7fffu + ((u >> 16) & 1u)) >> 16);
}

__device__ __forceinline__ u32 cvt_pk_bf16(float a, float b) {
  u32 r;
  asm("v_cvt_pk_bf16_f32 %0, %1, %2" : "=v"(r) : "v"(a), "v"(b));
  return r;  // lo = bf16(a), hi = bf16(b), RNE
}

__device__ __forceinline__ void gld_lds16(const u16* g, u16* l) {
  __builtin_amdgcn_global_load_lds((const __attribute__((address_space(1))) u32*)g,
                                   (__attribute__((address_space(3))) u32*)l, 16, 0, 0);
}

__global__ void cast_kernel(const float* __restrict__ s, u16* __restrict__ d, int n) {
  int i = (blockIdx.x * blockDim.x + threadIdx.x) * 4;
  if (i >= n) return;
  float4 f = *(const float4*)(s + i);
  ushort4 o;
  o.x = f2bf(f.x); o.y = f2bf(f.y); o.z = f2bf(f.z); o.w = f2bf(f.w);
  *(ushort4*)(d + i) = o;
}

struct CastArgs { const float* s[4]; u16* d[4]; float sc[4]; };
__global__ void cast4_kernel(CastArgs a) {
  int i = (blockIdx.x * blockDim.x + threadIdx.x) * 4;
  int w = i >> 20;
  int off = i & ((1 << 20) - 1);
  float sc = a.sc[w];
  float4 f = *(const float4*)(a.s[w] + off);
  ushort4 o;
  o.x = f2bf(f.x * sc); o.y = f2bf(f.y * sc); o.z = f2bf(f.z * sc); o.w = f2bf(f.w * sc);
  *(ushort4*)(a.d[w] + off) = o;
}

// ---- GEMM core: C[m,n] = sum_k A[m,k]*Bt[n,k], 128x128 tile, BK=64 ----
template <bool OUTF32>
__device__ __forceinline__ void gemm_core(const u16* __restrict__ A,
                                          const u16* __restrict__ Bt,
                                          float* __restrict__ Cf, u16* __restrict__ Cb,
                                          int Nn, int Kk, int m0, int n0,
                                          u16* As, u16* Bs) {
  const int tid = threadIdx.x, wave = tid >> 6, lane = tid & 63;
  const int quad = lane >> 4, col = lane & 15;
  const int wm = wave >> 1, wn = wave & 1;

  f32x4 acc[4][4];
#pragma unroll
  for (int i = 0; i < 4; i++)
#pragma unroll
    for (int j = 0; j < 4; j++) acc[i][j] = (f32x4){0.f, 0.f, 0.f, 0.f};

  for (int k0 = 0; k0 < Kk; k0 += 64) {
#pragma unroll
    for (int j = 0; j < 4; j++) {
      int g = (wave * 4 + j) * 64;
      int gl = g + lane;
      int r = gl >> 3, sl = gl & 7;
      int kof = (sl ^ (r & 7)) * 8;
      const u16* ga = A + (size_t)(m0 + r) * Kk + k0 + kof;
      gld_lds16(ga, &As[g * 8]);
      const u16* gb = Bt + (size_t)(n0 + r) * Kk + k0 + kof;
      gld_lds16(gb, &Bs[g * 8]);
    }
    __syncthreads();
#pragma unroll
    for (int kb = 0; kb < 2; kb++) {
      bf16x8 af[4], bfr[4];
#pragma unroll
      for (int mi = 0; mi < 4; mi++) {
        int R = wm * 64 + mi * 16 + col;
        af[mi] = *(const bf16x8*)&As[R * 64 + (((kb * 4 + quad) ^ (R & 7)) << 3)];
      }
#pragma unroll
      for (int ni = 0; ni < 4; ni++) {
        int R = wn * 64 + ni * 16 + col;
        bfr[ni] = *(const bf16x8*)&Bs[R * 64 + (((kb * 4 + quad) ^ (R & 7)) << 3)];
      }
#pragma unroll
      for (int mi = 0; mi < 4; mi++)
#pragma unroll
        for (int ni = 0; ni < 4; ni++)
          acc[mi][ni] = __builtin_amdgcn_mfma_f32_16x16x32_bf16(af[mi], bfr[ni], acc[mi][ni], 0, 0, 0);
    }
    __syncthreads();
  }
#pragma unroll
  for (int mi = 0; mi < 4; mi++)
#pragma unroll
    for (int ni = 0; ni < 4; ni++)
#pragma unroll
      for (int r = 0; r < 4; r++) {
        int row = m0 + wm * 64 + mi * 16 + quad * 4 + r;
        int cc = n0 + wn * 64 + ni * 16 + col;
        float v = acc[mi][ni][r];
        if (OUTF32) Cf[(size_t)row * Nn + cc] = v;
        else Cb[(size_t)row * Nn + cc] = f2bf(v);
      }
}

struct QkvArgs { const u16* bt[3]; u16* c[3]; };
__global__ __launch_bounds__(256) void gemm_qkv(const u16* __restrict__ A, QkvArgs q) {
  __shared__ __align__(16) u16 As[128 * 64];
  __shared__ __align__(16) u16 Bs[128 * 64];
  int sel = blockIdx.x >> 3;
  int n0 = (blockIdx.x & 7) * 128, m0 = blockIdx.y * 128;
  gemm_core<false>(A, q.bt[sel], nullptr, q.c[sel], D, D, m0, n0, As, Bs);
}

__global__ __launch_bounds__(256) void gemm_f32(const u16* __restrict__ A,
                                                const u16* __restrict__ Bt,
                                                float* __restrict__ C) {
  __shared__ __align__(16) u16 As[128 * 64];
  __shared__ __align__(16) u16 Bs[128 * 64];
  gemm_core<true>(A, Bt, C, nullptr, D, D, blockIdx.y * 128, blockIdx.x * 128, As, Bs);
}

// ---- flash attention, causal ----
// UNIFORM FINE-GRAINED PAIRS: 64-row q-sub-blocks (qsub 0..31, nkt=qsub+1
// k-tiles each) paired complementarily (31-i, i) -> EVERY block = exactly
// 33 k-iters. Grid 64bh x 16 pairs = 1024 uniform blocks = exactly 4/CU.
// 4 waves x 16 q-rows each (full M=16 MFMA tiles). LDS 40KB (Ks 16K + Vt
// 16K + Pw 8K) and halved accumulators (VGPR ~100) allow all 4 blocks/CU
// resident: 4 waves/SIMD, 2x R1's concurrency on a latency-bound kernel.
// Mechanics proven in R1: K double-buffered via global_load_lds DMA (source
// pre-swizzled, linear dest); V double-buffered regs->LDS transposed (slot
// = (key>>3)^(d&7), conflict-free b128); QK^T SWAPPED (mfma(K,Q)) so P
// packs with cvt_pk straight into swizzled Pw as 4 ds_write_b64/iter; PV
// is K32 MFMA with A-frags re-read from Pw (slot=(unit8)^(row&7)); row
// sums via ones-MFMA. Q pre-scaled by 0.125*log2e.
__global__ __launch_bounds__(256) void attn_kernel(const u16* __restrict__ Q,
                                                   const u16* __restrict__ K,
                                                   const u16* __restrict__ V,
                                                   u16* __restrict__ O) {
  __shared__ __align__(16) u16 Ks[2][2][64 * 32];  // [buf][d-half][key*32 + swz-slot]
  __shared__ __align__(16) u16 Vt[2][64 * 64];     // [buf] V^T [d][key-swizzled]
  __shared__ __align__(16) u16 Pw[4][16 * 64];     // per-wave P [q(16)][key-swizzled]
  const int tid = threadIdx.x, wave = tid >> 6, lane = tid & 63;
  const int quad = lane >> 4, col = lane & 15;
  const int bh = blockIdx.x, b = bh >> 4, h = bh & 15;
  const int pi = blockIdx.y;  // pair index 0..15
  const size_t base = (size_t)b * S * D + h * DK;

  // V staging distribution: thread handles keys (vk0, vk0+1) x 8 d's
  const int vk0 = (tid & 31) * 2;
  const int vdg = tid >> 5;  // d-group 0..7

  bf16x8 bones;
#pragma unroll
  for (int e = 0; e < 8; e++) bones[e] = (short)0x3F80;  // bf16 1.0

  // K DMA: linear LDS dest, source d-chunk pre-swizzled: chunk = slot ^ ((key>>1)&3)
  auto kdma = [&](int ktile, int buf) {
    int c = tid, cb = wave * 64;
    int kk = c >> 2;
    int dch = (c & 3) ^ ((kk >> 1) & 3);
    const u16* g0 = K + base + (size_t)(ktile * 64 + kk) * D + dch * 8;
    gld_lds16(g0, &Ks[buf][0][cb * 8]);
    gld_lds16(g0 + 32, &Ks[buf][1][cb * 8]);
  };
  auto vstage = [&](int buf, bf16x8 r0, bf16x8 r1) {
    int kgrp = vk0 >> 3, kin = vk0 & 7;
#pragma unroll
    for (int e = 0; e < 8; e++) {
      u32 val = ((u32)(u16)r0[e]) | ((u32)(u16)r1[e] << 16);
      int slot = (kgrp ^ e) & 7;  // d&7 == e
      *(u32*)&Vt[buf][(vdg * 8 + e) * 64 + (slot << 3) + kin] = val;
    }
  };

  for (int half = 0; half < 2; half++) {
    const int qsub = half ? pi : 31 - pi;  // big half first
    const int qw = qsub * 64 + wave * 16;
    const int nkt = qsub + 1;

    bf16x8 aq[2];
#pragma unroll
    for (int kb = 0; kb < 2; kb++)
      aq[kb] = *(const bf16x8*)(Q + base + (size_t)(qw + col) * D + kb * 32 + quad * 8);

    f32x4 ao[4], lacc;
    lacc = (f32x4){0.f, 0.f, 0.f, 0.f};
#pragma unroll
    for (int dg = 0; dg < 4; dg++) ao[dg] = (f32x4){0.f, 0.f, 0.f, 0.f};

    // regs A hold even V-tiles, regs B hold odd V-tiles
    bf16x8 vA0, vA1, vB0, vB1;
    {
      const u16* vp = V + base + (size_t)vk0 * D + vdg * 8;
      vA0 = *(const bf16x8*)vp; vA1 = *(const bf16x8*)(vp + D);
    }
    __syncthreads();  // previous half's LDS readers done before restaging
    kdma(0, 0);
    vstage(0, vA0, vA1);
    {  // V(1) -> B (tile 1 always in-bounds: keys 64..127 < S)
      const u16* vp = V + base + (size_t)(64 + vk0) * D + vdg * 8;
      vB0 = *(const bf16x8*)vp; vB1 = *(const bf16x8*)(vp + D);
    }

    for (int kt = 0; kt < nkt; kt++) {
      const int bf = kt & 1, nb = bf ^ 1, ph = kt & 1;
      __syncthreads();  // drains K(kt) DMA + V(kt+1) regs; publishes Vt[bf]
      const bool active = (kt * 64 <= qw + 15);  // wave-uniform
      if (kt + 1 < nkt) {
        kdma(kt + 1, nb);  // a full iteration for the DMA to land
        // stage V(kt+1): odd tiles from B, even from A
        vstage(nb, ph ? vA0 : vB0, ph ? vA1 : vB1);
        if (kt + 2 < nkt) {  // V(kt+2) -> (even ? A : B)
          const u16* vp = V + base + (size_t)((kt + 2) * 64 + vk0) * D + vdg * 8;
          if (ph) { vB0 = *(const bf16x8*)vp; vB1 = *(const bf16x8*)(vp + D); }
          else    { vA0 = *(const bf16x8*)vp; vA1 = *(const bf16x8*)(vp + D); }
        }
      }
      if (!active) continue;
      // K fragments from Ks[bf] (swizzle: slot = quad ^ ((key>>1)&3))
      bf16x8 bk0[4], bk1[4];
      const int ksl = ((quad ^ ((col >> 1) & 3)) & 3) << 3;
#pragma unroll
      for (int n16 = 0; n16 < 4; n16++) {
        bk0[n16] = *(const bf16x8*)&Ks[bf][0][(n16 * 16 + col) * 32 + ksl];
        bk1[n16] = *(const bf16x8*)&Ks[bf][1][(n16 * 16 + col) * 32 + ksl];
      }
      // Swapped QK^T: A = K (m = key), B = Q (n = q).
      // C[m = n16*16 + quad*4 + r][n = col]
      f32x4 sacc[4];
#pragma unroll
      for (int n16 = 0; n16 < 4; n16++) sacc[n16] = (f32x4){0.f, 0.f, 0.f, 0.f};
      __builtin_amdgcn_s_setprio(1);
#pragma unroll
      for (int n16 = 0; n16 < 4; n16++) {
        sacc[n16] = __builtin_amdgcn_mfma_f32_16x16x32_bf16(bk0[n16], aq[0], sacc[n16], 0, 0, 0);
        sacc[n16] = __builtin_amdgcn_mfma_f32_16x16x32_bf16(bk1[n16], aq[1], sacc[n16], 0, 0, 0);
      }
      __builtin_amdgcn_s_setprio(0);
      const bool full = (kt * 64 + 63) <= qw;  // wave-uniform: no masking
      // p = exp2(s); lane holds keys n16*16+quad*4+{0..3} for q = col
      // => cvt_pk pairs, one ds_write_b64 per n16 into swizzled Pw.
      {
        const int rsw = col & 7;
        const int qg = qw + col;
#pragma unroll
        for (int n16 = 0; n16 < 4; n16++) {
          float p0 = EXP2F(sacc[n16][0]);
          float p1 = EXP2F(sacc[n16][1]);
          float p2 = EXP2F(sacc[n16][2]);
          float p3 = EXP2F(sacc[n16][3]);
          if (!full) {
            int kg = kt * 64 + n16 * 16 + quad * 4;
            p0 = (kg + 0 > qg) ? 0.f : p0;
            p1 = (kg + 1 > qg) ? 0.f : p1;
            p2 = (kg + 2 > qg) ? 0.f : p2;
            p3 = (kg + 3 > qg) ? 0.f : p3;
          }
          u32 lo = cvt_pk_bf16(p0, p1);
          u32 hi = cvt_pk_bf16(p2, p3);
          int slot = ((n16 * 2 + (quad >> 1)) ^ rsw) & 7;
          *(u32x2*)&Pw[wave][col * 64 + (slot << 3) + ((quad & 1) << 2)] = (u32x2){lo, hi};
        }
      }
      // PV + ones-MFMA row sums (same-wave LDS write->read, no barrier)
      bf16x8 bv[2][4];
#pragma unroll
      for (int kb = 0; kb < 2; kb++)
#pragma unroll
        for (int dg = 0; dg < 4; dg++)
          bv[kb][dg] = *(const bf16x8*)&Vt[bf][(dg * 16 + col) * 64 + ((((kb * 4 + quad) ^ (col & 7)) & 7) << 3)];
      {
        const int rsw = col & 7;
        bf16x8 ap0 = *(const bf16x8*)&Pw[wave][col * 64 + (((quad ^ rsw) & 7) << 3)];
        bf16x8 ap1 = *(const bf16x8*)&Pw[wave][col * 64 + ((((4 + quad) ^ rsw) & 7) << 3)];
        __builtin_amdgcn_s_setprio(1);
#pragma unroll
        for (int dg = 0; dg < 4; dg++) {
          ao[dg] = __builtin_amdgcn_mfma_f32_16x16x32_bf16(ap0, bv[0][dg], ao[dg], 0, 0, 0);
          ao[dg] = __builtin_amdgcn_mfma_f32_16x16x32_bf16(ap1, bv[1][dg], ao[dg], 0, 0, 0);
        }
        lacc = __builtin_amdgcn_mfma_f32_16x16x32_bf16(ap0, bones, lacc, 0, 0, 0);
        lacc = __builtin_amdgcn_mfma_f32_16x16x32_bf16(ap1, bones, lacc, 0, 0, 0);
        __builtin_amdgcn_s_setprio(0);
      }
    }
    // epilogue: normalize + write O (16 q-rows per wave)
#pragma unroll
    for (int r = 0; r < 4; r++) {
      float inv = 1.f / lacc[r];
      int q = qw + quad * 4 + r;
#pragma unroll
      for (int dg = 0; dg < 4; dg++)
        O[base + (size_t)q * D + dg * 16 + col] = f2bf(ao[dg][r] * inv);
    }
  }
}

extern "C" void kernel_launch(void* const* d_in, const int* in_sizes, int n_in,
                              void* d_out, int out_size, void* d_ws, size_t ws_size,
                              hipStream_t stream) {
  const float* x  = (const float*)d_in[0];
  const float* Wq = (const float*)d_in[1];
  const float* Wk = (const float*)d_in[2];
  const float* Wv = (const float*)d_in[3];
  const float* Wo = (const float*)d_in[4];

  u16* xb  = (u16*)d_ws;
  u16* wqb = xb + (size_t)M * D;
  u16* wkb = wqb + (size_t)D * D;
  u16* wvb = wkb + (size_t)D * D;
  u16* wob = wvb + (size_t)D * D;
  u16* Qb  = wob + (size_t)D * D;
  u16* Kb  = Qb + (size_t)M * D;
  u16* Vb  = Kb + (size_t)M * D;
  u16* Ab  = xb;  // x dead after projections

  cast_kernel<<<M * D / 1024, 256, 0, stream>>>(x, xb, M * D);
  CastArgs ca;
  ca.s[0] = Wq; ca.s[1] = Wk; ca.s[2] = Wv; ca.s[3] = Wo;
  ca.d[0] = wqb; ca.d[1] = wkb; ca.d[2] = wvb; ca.d[3] = wob;
  ca.sc[0] = 0.18033688011112042f;  // 0.125 * log2(e) folded into Wq
  ca.sc[1] = 1.f; ca.sc[2] = 1.f; ca.sc[3] = 1.f;
  cast4_kernel<<<4 * D * D / 1024, 256, 0, stream>>>(ca);

  QkvArgs qa;
  qa.bt[0] = wqb; qa.bt[1] = wkb; qa.bt[2] = wvb;
  qa.c[0] = Qb; qa.c[1] = Kb; qa.c[2] = Vb;
  gemm_qkv<<<dim3(24, M / 128), 256, 0, stream>>>(xb, qa);

  attn_kernel<<<dim3(Bb * H, 16), 256, 0, stream>>>(Qb, Kb, Vb, Ab);

  gemm_f32<<<dim3(D / 128, M / 128), 256, 0, stream>>>(Ab, wob, (float*)d_out);
}

// Round 7
// 247.428 us; speedup vs baseline: 1.1174x; 1.1174x over previous
//
#include <hip/hip_runtime.h>

typedef __attribute__((ext_vector_type(8))) short bf16x8;
typedef __attribute__((ext_vector_type(4))) float f32x4;
typedef __attribute__((ext_vector_type(2))) unsigned int u32x2;
typedef unsigned int u32;
typedef unsigned short u16;

constexpr int Bb = 4, S = 2048, D = 1024, H = 16, DK = 64, M = Bb * S;

#if __has_builtin(__builtin_amdgcn_exp2f)
#define EXP2F __builtin_amdgcn_exp2f
#else
#define EXP2F exp2f
#endif

__device__ __forceinline__ u16 f2bf(float f) {
  u32 u = __float_as_uint(f);
  return (u16)((u + 0x7fffu + ((u >> 16) & 1u)) >> 16);
}

__device__ __forceinline__ u32 cvt_pk_bf16(float a, float b) {
  u32 r;
  asm("v_cvt_pk_bf16_f32 %0, %1, %2" : "=v"(r) : "v"(a), "v"(b));
  return r;  // lo = bf16(a), hi = bf16(b), RNE
}

__device__ __forceinline__ void gld_lds16(const u16* g, u16* l) {
  __builtin_amdgcn_global_load_lds((const __attribute__((address_space(1))) u32*)g,
                                   (__attribute__((address_space(3))) u32*)l, 16, 0, 0);
}

__global__ void cast_kernel(const float* __restrict__ s, u16* __restrict__ d, int n) {
  int i = (blockIdx.x * blockDim.x + threadIdx.x) * 4;
  if (i >= n) return;
  float4 f = *(const float4*)(s + i);
  ushort4 o;
  o.x = f2bf(f.x); o.y = f2bf(f.y); o.z = f2bf(f.z); o.w = f2bf(f.w);
  *(ushort4*)(d + i) = o;
}

struct CastArgs { const float* s[4]; u16* d[4]; float sc[4]; };
__global__ void cast4_kernel(CastArgs a) {
  int i = (blockIdx.x * blockDim.x + threadIdx.x) * 4;
  int w = i >> 20;
  int off = i & ((1 << 20) - 1);
  float sc = a.sc[w];
  float4 f = *(const float4*)(a.s[w] + off);
  ushort4 o;
  o.x = f2bf(f.x * sc); o.y = f2bf(f.y * sc); o.z = f2bf(f.z * sc); o.w = f2bf(f.w * sc);
  *(ushort4*)(a.d[w] + off) = o;
}

// ---- GEMM core: C[m,n] = sum_k A[m,k]*Bt[n,k], 128x128 tile, BK=64 ----
template <bool OUTF32>
__device__ __forceinline__ void gemm_core(const u16* __restrict__ A,
                                          const u16* __restrict__ Bt,
                                          float* __restrict__ Cf, u16* __restrict__ Cb,
                                          int Nn, int Kk, int m0, int n0,
                                          u16* As, u16* Bs) {
  const int tid = threadIdx.x, wave = tid >> 6, lane = tid & 63;
  const int quad = lane >> 4, col = lane & 15;
  const int wm = wave >> 1, wn = wave & 1;

  f32x4 acc[4][4];
#pragma unroll
  for (int i = 0; i < 4; i++)
#pragma unroll
    for (int j = 0; j < 4; j++) acc[i][j] = (f32x4){0.f, 0.f, 0.f, 0.f};

  for (int k0 = 0; k0 < Kk; k0 += 64) {
#pragma unroll
    for (int j = 0; j < 4; j++) {
      int g = (wave * 4 + j) * 64;
      int gl = g + lane;
      int r = gl >> 3, sl = gl & 7;
      int kof = (sl ^ (r & 7)) * 8;
      const u16* ga = A + (size_t)(m0 + r) * Kk + k0 + kof;
      gld_lds16(ga, &As[g * 8]);
      const u16* gb = Bt + (size_t)(n0 + r) * Kk + k0 + kof;
      gld_lds16(gb, &Bs[g * 8]);
    }
    __syncthreads();
#pragma unroll
    for (int kb = 0; kb < 2; kb++) {
      bf16x8 af[4], bfr[4];
#pragma unroll
      for (int mi = 0; mi < 4; mi++) {
        int R = wm * 64 + mi * 16 + col;
        af[mi] = *(const bf16x8*)&As[R * 64 + (((kb * 4 + quad) ^ (R & 7)) << 3)];
      }
#pragma unroll
      for (int ni = 0; ni < 4; ni++) {
        int R = wn * 64 + ni * 16 + col;
        bfr[ni] = *(const bf16x8*)&Bs[R * 64 + (((kb * 4 + quad) ^ (R & 7)) << 3)];
      }
#pragma unroll
      for (int mi = 0; mi < 4; mi++)
#pragma unroll
        for (int ni = 0; ni < 4; ni++)
          acc[mi][ni] = __builtin_amdgcn_mfma_f32_16x16x32_bf16(af[mi], bfr[ni], acc[mi][ni], 0, 0, 0);
    }
    __syncthreads();
  }
#pragma unroll
  for (int mi = 0; mi < 4; mi++)
#pragma unroll
    for (int ni = 0; ni < 4; ni++)
#pragma unroll
      for (int r = 0; r < 4; r++) {
        int row = m0 + wm * 64 + mi * 16 + quad * 4 + r;
        int cc = n0 + wn * 64 + ni * 16 + col;
        float v = acc[mi][ni][r];
        if (OUTF32) Cf[(size_t)row * Nn + cc] = v;
        else Cb[(size_t)row * Nn + cc] = f2bf(v);
      }
}

struct QkvArgs { const u16* bt[3]; u16* c[3]; };
__global__ __launch_bounds__(256) void gemm_qkv(const u16* __restrict__ A, QkvArgs q) {
  __shared__ __align__(16) u16 As[128 * 64];
  __shared__ __align__(16) u16 Bs[128 * 64];
  int sel = blockIdx.x >> 3;
  int n0 = (blockIdx.x & 7) * 128, m0 = blockIdx.y * 128;
  gemm_core<false>(A, q.bt[sel], nullptr, q.c[sel], D, D, m0, n0, As, Bs);
}

__global__ __launch_bounds__(256) void gemm_f32(const u16* __restrict__ A,
                                                const u16* __restrict__ Bt,
                                                float* __restrict__ C) {
  __shared__ __align__(16) u16 As[128 * 64];
  __shared__ __align__(16) u16 Bs[128 * 64];
  gemm_core<true>(A, Bt, C, nullptr, D, D, blockIdx.y * 128, blockIdx.x * 128, As, Bs);
}

// ---- flash attention, causal ----
// R1 structure (best verified: 85.5us): pair of 128-row q-blocks per block
// (15-p, p) => uniform 36 k-iters, 512 blocks. K double-buffered in LDS via
// global_load_lds DMA (source pre-swizzled, linear dest); V double-buffered
// regs->LDS transposed (slot=(key>>3)^(d&7), conflict-free b128); QK^T
// SWAPPED (mfma(K,Q)); P packed via cvt_pk into swizzled Pw (8 ds_write_b64)
// and re-read as K32 A-frags; row sums via ones-MFMA.
// R7 change: k-loop UNROLLED BY 2 (nkt always even) so bf/nb/ph are
// compile-time constants -> all LDS addresses lane-constant (hoisted once),
// V-reg ping-pong ternaries gone, global K/V pointers strength-reduced to
// += 64*D. Pure codegen streamlining targeting the 52% VALUBusy.
__global__ __launch_bounds__(256) void attn_kernel(const u16* __restrict__ Q,
                                                   const u16* __restrict__ K,
                                                   const u16* __restrict__ V,
                                                   u16* __restrict__ O) {
  __shared__ __align__(16) u16 Ks[2][2][64 * 32];  // [buf][d-half][key*32 + swz-slot]
  __shared__ __align__(16) u16 Vt[2][64 * 64];     // [buf] V^T [d][key-swizzled]
  __shared__ __align__(16) u16 Pw[4][32 * 64];     // per-wave P [q][key-swizzled]
  const int tid = threadIdx.x, wave = tid >> 6, lane = tid & 63;
  const int quad = lane >> 4, col = lane & 15;
  const int bh = blockIdx.x, b = bh >> 4, h = bh & 15;
  const int pair = blockIdx.y;  // 0..7
  const size_t base = (size_t)b * S * D + h * DK;

  const int vk0 = (tid & 31) * 2;  // V staging: keys (vk0, vk0+1) x 8 d's
  const int vdg = tid >> 5;        // d-group 0..7

  bf16x8 bones;
#pragma unroll
  for (int e = 0; e < 8; e++) bones[e] = (short)0x3F80;  // bf16 1.0

  // ---- hoisted lane-constant LDS addresses ----
  const int rsw = col & 7;
  const int ksl = ((quad ^ ((col >> 1) & 3)) & 3) << 3;
  const u16* kbase[2] = { &Ks[0][0][col * 32 + ksl], &Ks[1][0][col * 32 + ksl] };
  const int vsl0 = ((quad ^ rsw) & 7) << 3;          // slot offsets (elements)
  const int vsl1 = (((4 + quad) ^ rsw) & 7) << 3;
  const u16* vbase[2] = { &Vt[0][col * 64], &Vt[1][col * 64] };
  u16* pww[2] = { &Pw[wave][col * 64 + (quad & 1) * 4],
                  &Pw[wave][(16 + col) * 64 + (quad & 1) * 4] };
  int swof[4];
#pragma unroll
  for (int n16 = 0; n16 < 4; n16++)
    swof[n16] = (((n16 * 2 + (quad >> 1)) ^ rsw) & 7) << 3;
  const u16* apbase[2] = { &Pw[wave][col * 64], &Pw[wave][(16 + col) * 64] };
  // K DMA lane mapping (source d-chunk pre-swizzled: chunk = slot ^ ((key>>1)&3))
  const int kk = tid >> 2;
  const int dch = (tid & 3) ^ ((kk >> 1) & 3);
  const int cb = wave * 64;
  u16* dk[2][2] = { { &Ks[0][0][cb * 8], &Ks[0][1][cb * 8] },
                    { &Ks[1][0][cb * 8], &Ks[1][1][cb * 8] } };
  // V stage write addressing
  const int kgrp = vk0 >> 3, kin = vk0 & 7;
  u16* vwb[2] = { &Vt[0][vdg * 8 * 64 + kin], &Vt[1][vdg * 8 * 64 + kin] };
  int vwof[8];
#pragma unroll
  for (int e = 0; e < 8; e++) vwof[e] = e * 64 + ((kgrp ^ e) & 7) * 8;

  auto vstage = [&](const int buf, bf16x8 r0, bf16x8 r1) {
    u16* wb = vwb[buf];
#pragma unroll
    for (int e = 0; e < 8; e++) {
      u32 val = ((u32)(u16)r0[e]) | ((u32)(u16)r1[e] << 16);
      *(u32*)(wb + vwof[e]) = val;
    }
  };

  for (int half = 0; half < 2; half++) {
    const int qb = half ? pair : 15 - pair;
    const int qw = qb * 128 + wave * 32;
    const int nkt = 2 * qb + 2;  // even

    bf16x8 aq[2][2];
#pragma unroll
    for (int mi = 0; mi < 2; mi++)
#pragma unroll
      for (int kb = 0; kb < 2; kb++)
        aq[mi][kb] = *(const bf16x8*)(Q + base + (size_t)(qw + mi * 16 + col) * D + kb * 32 + quad * 8);

    f32x4 ao[2][4], lacc[2];
#pragma unroll
    for (int mi = 0; mi < 2; mi++) {
      lacc[mi] = (f32x4){0.f, 0.f, 0.f, 0.f};
#pragma unroll
      for (int dg = 0; dg < 4; dg++) ao[mi][dg] = (f32x4){0.f, 0.f, 0.f, 0.f};
    }

    // compute body for one k-tile; BF is compile-time per unrolled body
    auto compute = [&](const int BF, int kt) {
      const u16* kbK = kbase[BF];
      bf16x8 bk0[4], bk1[4];
#pragma unroll
      for (int n16 = 0; n16 < 4; n16++) {
        bk0[n16] = *(const bf16x8*)(kbK + n16 * 512);
        bk1[n16] = *(const bf16x8*)(kbK + n16 * 512 + 2048);
      }
      f32x4 sacc[2][4];
#pragma unroll
      for (int qi = 0; qi < 2; qi++)
#pragma unroll
        for (int n16 = 0; n16 < 4; n16++) sacc[qi][n16] = (f32x4){0.f, 0.f, 0.f, 0.f};
      __builtin_amdgcn_s_setprio(1);
#pragma unroll
      for (int qi = 0; qi < 2; qi++)
#pragma unroll
        for (int n16 = 0; n16 < 4; n16++) {
          sacc[qi][n16] = __builtin_amdgcn_mfma_f32_16x16x32_bf16(bk0[n16], aq[qi][0], sacc[qi][n16], 0, 0, 0);
          sacc[qi][n16] = __builtin_amdgcn_mfma_f32_16x16x32_bf16(bk1[n16], aq[qi][1], sacc[qi][n16], 0, 0, 0);
        }
      __builtin_amdgcn_s_setprio(0);
      const bool full = (kt * 64 + 63) <= qw;  // wave-uniform: no masking
#pragma unroll
      for (int qi = 0; qi < 2; qi++) {
        const int qg = qw + qi * 16 + col;
#pragma unroll
        for (int n16 = 0; n16 < 4; n16++) {
          float p0 = EXP2F(sacc[qi][n16][0]);
          float p1 = EXP2F(sacc[qi][n16][1]);
          float p2 = EXP2F(sacc[qi][n16][2]);
          float p3 = EXP2F(sacc[qi][n16][3]);
          if (!full) {
            int kg = kt * 64 + n16 * 16 + quad * 4;
            p0 = (kg + 0 > qg) ? 0.f : p0;
            p1 = (kg + 1 > qg) ? 0.f : p1;
            p2 = (kg + 2 > qg) ? 0.f : p2;
            p3 = (kg + 3 > qg) ? 0.f : p3;
          }
          u32 lo = cvt_pk_bf16(p0, p1);
          u32 hi = cvt_pk_bf16(p2, p3);
          *(u32x2*)(pww[qi] + swof[n16]) = (u32x2){lo, hi};
        }
      }
      // PV + ones-MFMA row sums (same-wave LDS write->read, in-order DS)
      const u16* vtB = vbase[BF];
      bf16x8 bv0[4], bv1[4];
#pragma unroll
      for (int dg = 0; dg < 4; dg++) {
        bv0[dg] = *(const bf16x8*)(vtB + dg * 1024 + vsl0);
        bv1[dg] = *(const bf16x8*)(vtB + dg * 1024 + vsl1);
      }
#pragma unroll
      for (int mi = 0; mi < 2; mi++) {
        bf16x8 ap0 = *(const bf16x8*)(apbase[mi] + vsl0);
        bf16x8 ap1 = *(const bf16x8*)(apbase[mi] + vsl1);
        __builtin_amdgcn_s_setprio(1);
#pragma unroll
        for (int dg = 0; dg < 4; dg++) {
          ao[mi][dg] = __builtin_amdgcn_mfma_f32_16x16x32_bf16(ap0, bv0[dg], ao[mi][dg], 0, 0, 0);
          ao[mi][dg] = __builtin_amdgcn_mfma_f32_16x16x32_bf16(ap1, bv1[dg], ao[mi][dg], 0, 0, 0);
        }
        lacc[mi] = __builtin_amdgcn_mfma_f32_16x16x32_bf16(ap0, bones, lacc[mi], 0, 0, 0);
        lacc[mi] = __builtin_amdgcn_mfma_f32_16x16x32_bf16(ap1, bones, lacc[mi], 0, 0, 0);
        __builtin_amdgcn_s_setprio(0);
      }
    };

    // ---- prologue ----
    bf16x8 vA0, vA1, vB0, vB1;
    const u16* gv = V + base + (size_t)vk0 * D + vdg * 8;  // V tile 0
    vA0 = *(const bf16x8*)gv;
    vA1 = *(const bf16x8*)(gv + D);
    __syncthreads();  // previous half's LDS readers done before restaging
    const u16* gk = K + base + (size_t)kk * D + dch * 8;   // K tile 0
    gld_lds16(gk, dk[0][0]);
    gld_lds16(gk + 32, dk[0][1]);
    gk += (size_t)64 * D;  // -> tile 1
    vstage(0, vA0, vA1);
    vB0 = *(const bf16x8*)(gv + (size_t)64 * D);           // V tile 1
    vB1 = *(const bf16x8*)(gv + (size_t)64 * D + D);
    gv += (size_t)128 * D;  // -> tile 2

    // ---- main loop, unrolled by 2 (bf = 0 then 1, compile-time) ----
    for (int kt = 0; kt < nkt; kt += 2) {
      // even body: bf=0, stage tile kt+1 -> buf1 from vB, load vA = tile kt+2
      __syncthreads();  // drains K(kt) DMA; publishes Vt[0]
      {
        // kt+1 < nkt always (nkt even)
        gld_lds16(gk, dk[1][0]);
        gld_lds16(gk + 32, dk[1][1]);
        gk += (size_t)64 * D;
        vstage(1, vB0, vB1);
        if (kt + 2 < nkt) {
          vA0 = *(const bf16x8*)gv;
          vA1 = *(const bf16x8*)(gv + D);
          gv += (size_t)64 * D;
        }
        if (kt * 64 <= qw + 31) compute(0, kt);
      }
      // odd body: bf=1, stage tile kt+2 -> buf0 from vA, load vB = tile kt+3
      __syncthreads();  // drains K(kt+1) DMA; publishes Vt[1]
      {
        const int kt1 = kt + 1;
        if (kt1 + 1 < nkt) {
          gld_lds16(gk, dk[0][0]);
          gld_lds16(gk + 32, dk[0][1]);
          gk += (size_t)64 * D;
          vstage(0, vA0, vA1);
          if (kt1 + 2 < nkt) {
            vB0 = *(const bf16x8*)gv;
            vB1 = *(const bf16x8*)(gv + D);
            gv += (size_t)64 * D;
          }
        }
        if (kt1 * 64 <= qw + 31) compute(1, kt1);
      }
    }
    // epilogue: normalize + write O
#pragma unroll
    for (int mi = 0; mi < 2; mi++)
#pragma unroll
      for (int r = 0; r < 4; r++) {
        float inv = 1.f / lacc[mi][r];
        int q = qw + mi * 16 + quad * 4 + r;
#pragma unroll
        for (int dg = 0; dg < 4; dg++)
          O[base + (size_t)q * D + dg * 16 + col] = f2bf(ao[mi][dg][r] * inv);
      }
  }
}

extern "C" void kernel_launch(void* const* d_in, const int* in_sizes, int n_in,
                              void* d_out, int out_size, void* d_ws, size_t ws_size,
                              hipStream_t stream) {
  const float* x  = (const float*)d_in[0];
  const float* Wq = (const float*)d_in[1];
  const float* Wk = (const float*)d_in[2];
  const float* Wv = (const float*)d_in[3];
  const float* Wo = (const float*)d_in[4];

  u16* xb  = (u16*)d_ws;
  u16* wqb = xb + (size_t)M * D;
  u16* wkb = wqb + (size_t)D * D;
  u16* wvb = wkb + (size_t)D * D;
  u16* wob = wvb + (size_t)D * D;
  u16* Qb  = wob + (size_t)D * D;
  u16* Kb  = Qb + (size_t)M * D;
  u16* Vb  = Kb + (size_t)M * D;
  u16* Ab  = xb;  // x dead after projections

  cast_kernel<<<M * D / 1024, 256, 0, stream>>>(x, xb, M * D);
  CastArgs ca;
  ca.s[0] = Wq; ca.s[1] = Wk; ca.s[2] = Wv; ca.s[3] = Wo;
  ca.d[0] = wqb; ca.d[1] = wkb; ca.d[2] = wvb; ca.d[3] = wob;
  ca.sc[0] = 0.18033688011112042f;  // 0.125 * log2(e) folded into Wq
  ca.sc[1] = 1.f; ca.sc[2] = 1.f; ca.sc[3] = 1.f;
  cast4_kernel<<<4 * D * D / 1024, 256, 0, stream>>>(ca);

  QkvArgs qa;
  qa.bt[0] = wqb; qa.bt[1] = wkb; qa.bt[2] = wvb;
  qa.c[0] = Qb; qa.c[1] = Kb; qa.c[2] = Vb;
  gemm_qkv<<<dim3(24, M / 128), 256, 0, stream>>>(xb, qa);

  attn_kernel<<<dim3(Bb * H, 8), 256, 0, stream>>>(Qb, Kb, Vb, Ab);

  gemm_f32<<<dim3(D / 128, M / 128), 256, 0, stream>>>(Ab, wob, (float*)d_out);
}